// Round 5
// baseline (204.433 us; speedup 1.0000x reference)
//
#include <hip/hip_runtime.h>

typedef unsigned short u16;
typedef unsigned short u16x8 __attribute__((ext_vector_type(8)));
typedef __bf16 bf16x8 __attribute__((ext_vector_type(8)));
typedef float f32x4 __attribute__((ext_vector_type(4)));

#define NN 4096
#define KD 512
#define HD 512
#define CAP 96   // per-row edge cap; mean 41, sigma 6.4 -> P(>96) ~ 0

__device__ __forceinline__ u16 f2bf(float f) {
    unsigned u = __builtin_bit_cast(unsigned, f);
    u += 0x7fffu + ((u >> 16) & 1u);
    return (u16)(u >> 16);
}
__device__ __forceinline__ float bf2f(u16 u) {
    return __builtin_bit_cast(float, ((unsigned)u) << 16);
}
__device__ __forceinline__ int permj(int j) { return ((j & 7) << 6) | (j >> 3); }

#define GLOAD16(gp, lp) \
    __builtin_amdgcn_global_load_lds((const __attribute__((address_space(1))) void*)(gp), \
                                     (__attribute__((address_space(3))) void*)(lp), 16, 0, 0)

// ---- fused prep: h->bf16  |  W^T (1536x512) bf16 head-major + bias ----
__global__ __launch_bounds__(256) void k_prep(const float4* __restrict__ h4,
        u16* __restrict__ hb,
        const float* __restrict__ Wq, const float* __restrict__ Wk,
        const float* __restrict__ Wv, const float* __restrict__ bq,
        const float* __restrict__ bk, const float* __restrict__ bv,
        u16* __restrict__ wt, float* __restrict__ pbias)
{
    __shared__ float tile[32][33];
    const int tid = threadIdx.x;
    if (blockIdx.x < 2048) {
        int i = blockIdx.x * 256 + tid;
        float4 f = h4[i];
        ((ushort4*)hb)[i] = make_ushort4(f2bf(f.x), f2bf(f.y), f2bf(f.z), f2bf(f.w));
        return;
    }
    const int b2 = blockIdx.x - 2048;              // 0..767
    const int jb = b2 & 15, kb = (b2 >> 4) & 15, z = b2 >> 8;
    const float* W = (z == 0) ? Wq : ((z == 1) ? Wk : Wv);
    const float scale = (z == 0) ? 0.125f : 1.0f;
    const int j0 = jb * 32, k0 = kb * 32;
    const int tx = tid & 31, ty = tid >> 5;
    #pragma unroll
    for (int r = 0; r < 32; r += 8)
        tile[ty + r][tx] = W[(size_t)(k0 + ty + r) * HD + j0 + tx];
    __syncthreads();
    #pragma unroll
    for (int r = 0; r < 32; r += 8) {
        int j = j0 + ty + r;
        wt[(size_t)(z * 512 + permj(j)) * KD + k0 + tx] = f2bf(scale * tile[tx][ty + r]);
    }
    if (kb == 0 && ty == 0) {
        int j = j0 + tx;
        float b = (z == 0) ? bq[j] * 0.125f : ((z == 1) ? bk[j] : bv[j]);
        pbias[z * 512 + permj(j)] = b;
    }
}

// ---- QKV GEMM (m97-style) with fused v-colsum; q output bf16 ----
__global__ __launch_bounds__(256) void k_gemm(const u16* __restrict__ hb,
        const u16* __restrict__ wt, const float* __restrict__ pbias,
        u16* __restrict__ qbuf, u16* __restrict__ kbuf, u16* __restrict__ vbuf,
        float* __restrict__ colsum)
{
    __shared__ u16 As[128 * 64];
    __shared__ u16 Bs[128 * 64];
    const int tid = threadIdx.x;
    const int w = tid >> 6, lane = tid & 63;
    const int wr = w >> 1, wc = w & 1;
    const int l16 = lane & 15, half = lane >> 4;
    const int row0 = blockIdx.x * 128, col0 = blockIdx.y * 128;
    const int la = lane & 7, lb = lane >> 3;
    const int swcol = ((la ^ lb) << 3);

    const u16* gA[4]; const u16* gB[4];
    u16* lA[4]; u16* lB[4];
    #pragma unroll
    for (int s = 0; s < 4; ++s) {
        int i = w * 4 + s;
        gA[s] = hb + (size_t)(row0 + 8 * i + lb) * KD + swcol;
        gB[s] = wt + (size_t)(col0 + 8 * i + lb) * KD + swcol;
        lA[s] = As + i * 512;
        lB[s] = Bs + i * 512;
    }

    f32x4 acc[4][4] = {};

    for (int kk = 0; kk < KD; kk += 64) {
        #pragma unroll
        for (int s = 0; s < 4; ++s) {
            GLOAD16(gA[s] + kk, lA[s]);
            GLOAD16(gB[s] + kk, lB[s]);
        }
        __syncthreads();
        #pragma unroll
        for (int kk2 = 0; kk2 < 2; ++kk2) {
            bf16x8 af[4], bf[4];
            #pragma unroll
            for (int mi = 0; mi < 4; ++mi) {
                int row = wr * 64 + mi * 16 + l16;
                int off = row * 128 + (((kk2 << 6) | (half << 4)) ^ ((l16 & 7) << 4));
                af[mi] = *(const bf16x8*)((const char*)As + off);
            }
            #pragma unroll
            for (int ni = 0; ni < 4; ++ni) {
                int row = wc * 64 + ni * 16 + l16;
                int off = row * 128 + (((kk2 << 6) | (half << 4)) ^ ((l16 & 7) << 4));
                bf[ni] = *(const bf16x8*)((const char*)Bs + off);
            }
            #pragma unroll
            for (int mi = 0; mi < 4; ++mi)
                #pragma unroll
                for (int ni = 0; ni < 4; ++ni)
                    acc[mi][ni] = __builtin_amdgcn_mfma_f32_16x16x32_bf16(
                        af[mi], bf[ni], acc[mi][ni], 0, 0, 0);
        }
        __syncthreads();
    }

    const int seg = blockIdx.y >> 2;   // 0=q 1=k 2=v
    #pragma unroll
    for (int ni = 0; ni < 4; ++ni) {
        int j = col0 + wc * 64 + ni * 16 + l16;
        float bj = pbias[j];
        float csum = 0.f;
        #pragma unroll
        for (int mi = 0; mi < 4; ++mi) {
            #pragma unroll
            for (int r = 0; r < 4; ++r) {
                int m = row0 + wr * 64 + mi * 16 + half * 4 + r;
                float val = acc[mi][ni][r] + bj;
                if (seg == 0)      qbuf[(size_t)m * 512 + j] = f2bf(val);
                else if (seg == 1) kbuf[(size_t)m * 512 + (j - 512)] = f2bf(val);
                else             { vbuf[(size_t)m * 512 + (j - 1024)] = f2bf(val); csum += val; }
            }
        }
        if (seg == 2) {
            csum += __shfl_xor(csum, 16);
            csum += __shfl_xor(csum, 32);
            if (lane < 16) atomicAdd(&colsum[j - 1024], csum);
        }
    }
}

// ---- fused sparse attention: 2 rows/block, 4 waves (2 per row, edge-parity split) ----
__global__ __launch_bounds__(256) void k_attn(const float4* __restrict__ A4,
        const u16* __restrict__ qbuf, const u16* __restrict__ kbuf,
        const u16* __restrict__ vbuf, const float* __restrict__ colsum,
        float* __restrict__ out)
{
    const int tid = threadIdx.x, w = tid >> 6, lane = tid & 63;
    const int n0 = blockIdx.x * 2;
    const int row = w & 1, seg = w >> 1;
    __shared__ u16   s_q[2][512];        // bf16 q, 2 KB
    __shared__ u16   s_idx[2][CAP];
    __shared__ u16   s_c[2][CAP][8];     // bf16 coefs, 3 KB
    __shared__ float s_red[2][2][512];   // [seg][row][h*64+d], 8 KB
    __shared__ int   s_cnt[2];

    if (tid < 2) s_cnt[tid] = 0;
    // q (1024 bf16)
    ((ushort4*)&s_q[0][0])[tid] = ((const ushort4*)(qbuf + (size_t)n0 * 512))[tid];
    __syncthreads();

    // A-scan: 2 rows = 2048 float4
    {
        const float4* arow = A4 + (size_t)n0 * 1024;
        #pragma unroll
        for (int ii = 0; ii < 8; ++ii) {
            int i = ii * 256 + tid;
            float4 a = arow[i];
            if (a.x != 0.f || a.y != 0.f || a.z != 0.f || a.w != 0.f) {
                int r = i >> 10, m0 = (i & 1023) * 4;
                if (a.x != 0.f) { int p = atomicAdd(&s_cnt[r], 1); if (p < CAP) s_idx[r][p] = (u16)m0; }
                if (a.y != 0.f) { int p = atomicAdd(&s_cnt[r], 1); if (p < CAP) s_idx[r][p] = (u16)(m0 + 1); }
                if (a.z != 0.f) { int p = atomicAdd(&s_cnt[r], 1); if (p < CAP) s_idx[r][p] = (u16)(m0 + 2); }
                if (a.w != 0.f) { int p = atomicAdd(&s_cnt[r], 1); if (p < CAP) s_idx[r][p] = (u16)(m0 + 3); }
            }
        }
    }
    __syncthreads();
    const int cnt = min(s_cnt[row], CAP);

    // ---- Phase 1: scores, lane-per-edge (edges of parity `seg`) ----
    {
        const int e = 2 * lane + seg;
        if (e < cnt) {
            const int m = s_idx[row][e];
            const u16* kr = kbuf + (size_t)m * 512;
            float acc8[8] = {0.f,0.f,0.f,0.f,0.f,0.f,0.f,0.f};
            #pragma unroll 8
            for (int c = 0; c < 64; ++c) {
                u16x8 kv = *(const u16x8*)(kr + c * 8);
                u16x8 qv = *(const u16x8*)&s_q[row][c * 8];
                float p = bf2f(qv[0])*bf2f(kv[0]) + bf2f(qv[1])*bf2f(kv[1])
                        + bf2f(qv[2])*bf2f(kv[2]) + bf2f(qv[3])*bf2f(kv[3])
                        + bf2f(qv[4])*bf2f(kv[4]) + bf2f(qv[5])*bf2f(kv[5])
                        + bf2f(qv[6])*bf2f(kv[6]) + bf2f(qv[7])*bf2f(kv[7]);
                acc8[c >> 3] += p;
            }
            float mx = acc8[0];
            #pragma unroll
            for (int i = 1; i < 8; ++i) mx = fmaxf(mx, acc8[i]);
            float Z = 0.f;
            #pragma unroll
            for (int i = 0; i < 8; ++i) { acc8[i] = __expf(acc8[i] - mx); Z += acc8[i]; }
            const float rz = 1.f / Z;
            u16x8 st;
            #pragma unroll
            for (int i = 0; i < 8; ++i) st[i] = f2bf(acc8[i] * rz - 0.125f);
            *(u16x8*)&s_c[row][e][0] = st;
        }
    }
    // no barrier: phase 2 reads only coefs this wave wrote (same edge parity)

    // ---- Phase 2: PV, wave-per-edge over parity `seg`, register accumulators ----
    const int hh = lane >> 3;
    float acc8[8] = {0.f,0.f,0.f,0.f,0.f,0.f,0.f,0.f};
    {
        int e = seg;
        for (; e + 6 < cnt; e += 8) {
            int m0 = s_idx[row][e],     m1 = s_idx[row][e + 2];
            int m2 = s_idx[row][e + 4], m3 = s_idx[row][e + 6];
            float c0 = bf2f(s_c[row][e][hh]),     c1 = bf2f(s_c[row][e + 2][hh]);
            float c2 = bf2f(s_c[row][e + 4][hh]), c3 = bf2f(s_c[row][e + 6][hh]);
            u16x8 v0 = *(const u16x8*)(vbuf + (size_t)m0 * 512 + lane * 8);
            u16x8 v1 = *(const u16x8*)(vbuf + (size_t)m1 * 512 + lane * 8);
            u16x8 v2 = *(const u16x8*)(vbuf + (size_t)m2 * 512 + lane * 8);
            u16x8 v3 = *(const u16x8*)(vbuf + (size_t)m3 * 512 + lane * 8);
            #pragma unroll
            for (int j = 0; j < 8; ++j)
                acc8[j] += c0*bf2f(v0[j]) + c1*bf2f(v1[j]) + c2*bf2f(v2[j]) + c3*bf2f(v3[j]);
        }
        for (; e < cnt; e += 2) {
            int m = s_idx[row][e];
            float c = bf2f(s_c[row][e][hh]);
            u16x8 vv = *(const u16x8*)(vbuf + (size_t)m * 512 + lane * 8);
            #pragma unroll
            for (int j = 0; j < 8; ++j) acc8[j] += c * bf2f(vv[j]);
        }
    }
    {
        f32x4 r0, r1;
        r0[0]=acc8[0]; r0[1]=acc8[1]; r0[2]=acc8[2]; r0[3]=acc8[3];
        r1[0]=acc8[4]; r1[1]=acc8[5]; r1[2]=acc8[6]; r1[3]=acc8[7];
        *(f32x4*)&s_red[seg][row][lane * 8]     = r0;
        *(f32x4*)&s_red[seg][row][lane * 8 + 4] = r1;
    }
    __syncthreads();

    // epilogue: 1024 outputs
    #pragma unroll
    for (int p = 0; p < 4; ++p) {
        int idx = p * 256 + tid;
        int rr = idx >> 9, i2 = idx & 511;
        int hh2 = i2 >> 6, d = i2 & 63;
        float val = s_red[0][rr][i2] + s_red[1][rr][i2] + 0.125f * colsum[i2];
        out[(size_t)hh2 * (NN * 64) + (size_t)(n0 + rr) * 64 + d] = val;
    }
}

extern "C" void kernel_launch(void* const* d_in, const int* in_sizes, int n_in,
                              void* d_out, int out_size, void* d_ws, size_t ws_size,
                              hipStream_t stream)
{
    const float* A  = (const float*)d_in[0];
    const float* h  = (const float*)d_in[1];
    const float* Wq = (const float*)d_in[2];
    const float* bq = (const float*)d_in[3];
    const float* Wk = (const float*)d_in[4];
    const float* bk = (const float*)d_in[5];
    const float* Wv = (const float*)d_in[6];
    const float* bv = (const float*)d_in[7];
    float* out = (float*)d_out;

    char* ws = (char*)d_ws;
    u16*   qbuf   = (u16*)(ws);                           // 4 MB
    u16*   kbuf   = (u16*)(ws + (4u  << 20));             // 4 MB
    u16*   vbuf   = (u16*)(ws + (8u  << 20));             // 4 MB
    u16*   hb     = (u16*)(ws + (12u << 20));             // 4 MB
    u16*   wt     = (u16*)(ws + (16u << 20));             // 1.5 MB
    float* pbias  = (float*)(ws + (18u << 20));           // 6 KB
    float* colsum = (float*)(ws + (18u << 20) + 8192);    // 2 KB

    hipMemsetAsync(colsum, 0, 512 * sizeof(float), stream);
    k_prep<<<dim3(2816), dim3(256), 0, stream>>>((const float4*)h, hb,
            Wq, Wk, Wv, bq, bk, bv, wt, pbias);
    k_gemm<<<dim3(32, 12), dim3(256), 0, stream>>>(hb, wt, pbias, qbuf, kbuf, vbuf, colsum);
    k_attn<<<dim3(2048), dim3(256), 0, stream>>>((const float4*)A, qbuf, kbuf, vbuf, colsum, out);
}

// Round 6
// 197.718 us; speedup vs baseline: 1.0340x; 1.0340x over previous
//
#include <hip/hip_runtime.h>

typedef unsigned short u16;
typedef unsigned short u16x8 __attribute__((ext_vector_type(8)));
typedef __bf16 bf16x8 __attribute__((ext_vector_type(8)));
typedef float f32x4 __attribute__((ext_vector_type(4)));

#define NN 4096
#define KD 512
#define HD 512
#define CAP 96   // per-row edge cap; mean 41, sigma 6.4 -> P(>96) ~ 0

__device__ __forceinline__ u16 f2bf(float f) {
    unsigned u = __builtin_bit_cast(unsigned, f);
    u += 0x7fffu + ((u >> 16) & 1u);
    return (u16)(u >> 16);
}
__device__ __forceinline__ float bf2f(u16 u) {
    return __builtin_bit_cast(float, ((unsigned)u) << 16);
}
__device__ __forceinline__ int permj(int j) { return ((j & 7) << 6) | (j >> 3); }

#define GLOAD16(gp, lp) \
    __builtin_amdgcn_global_load_lds((const __attribute__((address_space(1))) void*)(gp), \
                                     (__attribute__((address_space(3))) void*)(lp), 16, 0, 0)

// ---- fused prep: h->bf16  |  W^T (1536x512) bf16 head-major + bias ----
__global__ __launch_bounds__(256) void k_prep(const float4* __restrict__ h4,
        u16* __restrict__ hb,
        const float* __restrict__ Wq, const float* __restrict__ Wk,
        const float* __restrict__ Wv, const float* __restrict__ bq,
        const float* __restrict__ bk, const float* __restrict__ bv,
        u16* __restrict__ wt, float* __restrict__ pbias)
{
    __shared__ float tile[32][33];
    const int tid = threadIdx.x;
    if (blockIdx.x < 2048) {
        int i = blockIdx.x * 256 + tid;
        float4 f = h4[i];
        ((ushort4*)hb)[i] = make_ushort4(f2bf(f.x), f2bf(f.y), f2bf(f.z), f2bf(f.w));
        return;
    }
    const int b2 = blockIdx.x - 2048;              // 0..767
    const int jb = b2 & 15, kb = (b2 >> 4) & 15, z = b2 >> 8;
    const float* W = (z == 0) ? Wq : ((z == 1) ? Wk : Wv);
    const float scale = (z == 0) ? 0.125f : 1.0f;
    const int j0 = jb * 32, k0 = kb * 32;
    const int tx = tid & 31, ty = tid >> 5;
    #pragma unroll
    for (int r = 0; r < 32; r += 8)
        tile[ty + r][tx] = W[(size_t)(k0 + ty + r) * HD + j0 + tx];
    __syncthreads();
    #pragma unroll
    for (int r = 0; r < 32; r += 8) {
        int j = j0 + ty + r;
        wt[(size_t)(z * 512 + permj(j)) * KD + k0 + tx] = f2bf(scale * tile[tx][ty + r]);
    }
    if (kb == 0 && ty == 0) {
        int j = j0 + tx;
        float b = (z == 0) ? bq[j] * 0.125f : ((z == 1) ? bk[j] : bv[j]);
        pbias[z * 512 + permj(j)] = b;
    }
}

// ---- QKV GEMM (m97-style) with fused v-colsum; q output bf16 ----
__global__ __launch_bounds__(256) void k_gemm(const u16* __restrict__ hb,
        const u16* __restrict__ wt, const float* __restrict__ pbias,
        u16* __restrict__ qbuf, u16* __restrict__ kbuf, u16* __restrict__ vbuf,
        float* __restrict__ colsum)
{
    __shared__ u16 As[128 * 64];
    __shared__ u16 Bs[128 * 64];
    const int tid = threadIdx.x;
    const int w = tid >> 6, lane = tid & 63;
    const int wr = w >> 1, wc = w & 1;
    const int l16 = lane & 15, half = lane >> 4;
    const int row0 = blockIdx.x * 128, col0 = blockIdx.y * 128;
    const int la = lane & 7, lb = lane >> 3;
    const int swcol = ((la ^ lb) << 3);

    const u16* gA[4]; const u16* gB[4];
    u16* lA[4]; u16* lB[4];
    #pragma unroll
    for (int s = 0; s < 4; ++s) {
        int i = w * 4 + s;
        gA[s] = hb + (size_t)(row0 + 8 * i + lb) * KD + swcol;
        gB[s] = wt + (size_t)(col0 + 8 * i + lb) * KD + swcol;
        lA[s] = As + i * 512;
        lB[s] = Bs + i * 512;
    }

    f32x4 acc[4][4] = {};

    for (int kk = 0; kk < KD; kk += 64) {
        #pragma unroll
        for (int s = 0; s < 4; ++s) {
            GLOAD16(gA[s] + kk, lA[s]);
            GLOAD16(gB[s] + kk, lB[s]);
        }
        __syncthreads();
        #pragma unroll
        for (int kk2 = 0; kk2 < 2; ++kk2) {
            bf16x8 af[4], bf[4];
            #pragma unroll
            for (int mi = 0; mi < 4; ++mi) {
                int row = wr * 64 + mi * 16 + l16;
                int off = row * 128 + (((kk2 << 6) | (half << 4)) ^ ((l16 & 7) << 4));
                af[mi] = *(const bf16x8*)((const char*)As + off);
            }
            #pragma unroll
            for (int ni = 0; ni < 4; ++ni) {
                int row = wc * 64 + ni * 16 + l16;
                int off = row * 128 + (((kk2 << 6) | (half << 4)) ^ ((l16 & 7) << 4));
                bf[ni] = *(const bf16x8*)((const char*)Bs + off);
            }
            #pragma unroll
            for (int mi = 0; mi < 4; ++mi)
                #pragma unroll
                for (int ni = 0; ni < 4; ++ni)
                    acc[mi][ni] = __builtin_amdgcn_mfma_f32_16x16x32_bf16(
                        af[mi], bf[ni], acc[mi][ni], 0, 0, 0);
        }
        __syncthreads();
    }

    const int seg = blockIdx.y >> 2;   // 0=q 1=k 2=v
    #pragma unroll
    for (int ni = 0; ni < 4; ++ni) {
        int j = col0 + wc * 64 + ni * 16 + l16;
        float bj = pbias[j];
        float csum = 0.f;
        #pragma unroll
        for (int mi = 0; mi < 4; ++mi) {
            #pragma unroll
            for (int r = 0; r < 4; ++r) {
                int m = row0 + wr * 64 + mi * 16 + half * 4 + r;
                float val = acc[mi][ni][r] + bj;
                if (seg == 0)      qbuf[(size_t)m * 512 + j] = f2bf(val);
                else if (seg == 1) kbuf[(size_t)m * 512 + (j - 512)] = f2bf(val);
                else             { vbuf[(size_t)m * 512 + (j - 1024)] = f2bf(val); csum += val; }
            }
        }
        if (seg == 2) {
            csum += __shfl_xor(csum, 16);
            csum += __shfl_xor(csum, 32);
            if (lane < 16) atomicAdd(&colsum[j - 1024], csum);
        }
    }
}

// ---- fused sparse attention: 2 rows/block, 4 waves (2 per row) ----
// Phase 1: (edge x head) per lane — 8 edges/wave concurrent, chain depth 8.
// Phase 2: wave-per-edge PV over the same batches (no inter-phase barrier).
__global__ __launch_bounds__(256, 4) void k_attn(const float4* __restrict__ A4,
        const u16* __restrict__ qbuf, const u16* __restrict__ kbuf,
        const u16* __restrict__ vbuf, const float* __restrict__ colsum,
        float* __restrict__ out)
{
    const int tid = threadIdx.x, w = tid >> 6, lane = tid & 63;
    const int n0 = blockIdx.x * 2;
    const int row = w & 1;        // which of the 2 rows this wave serves
    const int p = w >> 1;         // batch parity within the row's wave pair
    __shared__ u16   s_q[2][512];        // bf16 q, 2 KB
    __shared__ u16   s_idx[2][CAP];      // 384 B
    __shared__ float s_c[2][CAP][8];     // f32 coefs, 6 KB
    __shared__ float s_red[2][2][512];   // [p][row][h*64+d], 8 KB
    __shared__ int   s_cnt[2];

    if (tid < 2) s_cnt[tid] = 0;
    ((ushort4*)&s_q[0][0])[tid] = ((const ushort4*)(qbuf + (size_t)n0 * 512))[tid];
    __syncthreads();

    // A-scan: 2 rows = 2048 float4
    {
        const float4* arow = A4 + (size_t)n0 * 1024;
        #pragma unroll
        for (int ii = 0; ii < 8; ++ii) {
            int i = ii * 256 + tid;
            float4 a = arow[i];
            if (a.x != 0.f || a.y != 0.f || a.z != 0.f || a.w != 0.f) {
                int r = i >> 10, m0 = (i & 1023) * 4;
                if (a.x != 0.f) { int q = atomicAdd(&s_cnt[r], 1); if (q < CAP) s_idx[r][q] = (u16)m0; }
                if (a.y != 0.f) { int q = atomicAdd(&s_cnt[r], 1); if (q < CAP) s_idx[r][q] = (u16)(m0 + 1); }
                if (a.z != 0.f) { int q = atomicAdd(&s_cnt[r], 1); if (q < CAP) s_idx[r][q] = (u16)(m0 + 2); }
                if (a.w != 0.f) { int q = atomicAdd(&s_cnt[r], 1); if (q < CAP) s_idx[r][q] = (u16)(m0 + 3); }
            }
        }
    }
    __syncthreads();
    const int cnt = min(s_cnt[row], CAP);

    // ---- Phase 1: scores. lane = (edge-in-batch, head) ----
    {
        const int eh_h = lane & 7;      // head
        const int eh_e = lane >> 3;     // edge within batch of 8
        // hoist this head's q chunk (64 bf16 = 32 VGPRs)
        u16x8 qreg[8];
        #pragma unroll
        for (int it = 0; it < 8; ++it)
            qreg[it] = *(const u16x8*)&s_q[row][eh_h * 64 + it * 8];

        for (int b = p; b * 8 < cnt; b += 2) {
            const int e = b * 8 + eh_e;
            const bool act = e < cnt;
            const int m = s_idx[row][act ? e : 0];
            const u16* kr = kbuf + (size_t)m * 512 + eh_h * 64;
            u16x8 kv[8];
            #pragma unroll
            for (int it = 0; it < 8; ++it) kv[it] = *(const u16x8*)(kr + it * 8);
            float s = 0.f;
            #pragma unroll
            for (int it = 0; it < 8; ++it)
                #pragma unroll
                for (int j = 0; j < 8; ++j)
                    s += bf2f(qreg[it][j]) * bf2f(kv[it][j]);
            // softmax across 8 heads = 8 lanes of this edge group
            float mx = fmaxf(s, __shfl_xor(s, 1));
            mx = fmaxf(mx, __shfl_xor(mx, 2));
            mx = fmaxf(mx, __shfl_xor(mx, 4));
            float ex = __expf(s - mx);
            float Z = ex + __shfl_xor(ex, 1);
            Z += __shfl_xor(Z, 2);
            Z += __shfl_xor(Z, 4);
            if (act) s_c[row][e][eh_h] = ex / Z - 0.125f;
        }
    }
    // no barrier: phase 2 consumes only this wave's own batches

    // ---- Phase 2: PV, wave-per-edge over own batches ----
    const int hh = lane >> 3;
    float acc8[8] = {0.f,0.f,0.f,0.f,0.f,0.f,0.f,0.f};
    for (int b = p; b * 8 < cnt; b += 2) {
        const int lim = min(cnt, b * 8 + 8);
        int e = b * 8;
        for (; e + 3 < lim; e += 4) {
            int m0 = s_idx[row][e],     m1 = s_idx[row][e + 1];
            int m2 = s_idx[row][e + 2], m3 = s_idx[row][e + 3];
            float c0 = s_c[row][e][hh],     c1 = s_c[row][e + 1][hh];
            float c2 = s_c[row][e + 2][hh], c3 = s_c[row][e + 3][hh];
            u16x8 v0 = *(const u16x8*)(vbuf + (size_t)m0 * 512 + lane * 8);
            u16x8 v1 = *(const u16x8*)(vbuf + (size_t)m1 * 512 + lane * 8);
            u16x8 v2 = *(const u16x8*)(vbuf + (size_t)m2 * 512 + lane * 8);
            u16x8 v3 = *(const u16x8*)(vbuf + (size_t)m3 * 512 + lane * 8);
            #pragma unroll
            for (int j = 0; j < 8; ++j)
                acc8[j] += c0*bf2f(v0[j]) + c1*bf2f(v1[j]) + c2*bf2f(v2[j]) + c3*bf2f(v3[j]);
        }
        for (; e < lim; ++e) {
            int m = s_idx[row][e];
            float c = s_c[row][e][hh];
            u16x8 vv = *(const u16x8*)(vbuf + (size_t)m * 512 + lane * 8);
            #pragma unroll
            for (int j = 0; j < 8; ++j) acc8[j] += c * bf2f(vv[j]);
        }
    }
    {
        f32x4 r0, r1;
        r0[0]=acc8[0]; r0[1]=acc8[1]; r0[2]=acc8[2]; r0[3]=acc8[3];
        r1[0]=acc8[4]; r1[1]=acc8[5]; r1[2]=acc8[6]; r1[3]=acc8[7];
        *(f32x4*)&s_red[p][row][lane * 8]     = r0;
        *(f32x4*)&s_red[p][row][lane * 8 + 4] = r1;
    }
    __syncthreads();

    // epilogue: 1024 outputs
    #pragma unroll
    for (int pp = 0; pp < 4; ++pp) {
        int idx = pp * 256 + tid;
        int rr = idx >> 9, i2 = idx & 511;
        int hh2 = i2 >> 6, d = i2 & 63;
        float val = s_red[0][rr][i2] + s_red[1][rr][i2] + 0.125f * colsum[i2];
        out[(size_t)hh2 * (NN * 64) + (size_t)(n0 + rr) * 64 + d] = val;
    }
}

extern "C" void kernel_launch(void* const* d_in, const int* in_sizes, int n_in,
                              void* d_out, int out_size, void* d_ws, size_t ws_size,
                              hipStream_t stream)
{
    const float* A  = (const float*)d_in[0];
    const float* h  = (const float*)d_in[1];
    const float* Wq = (const float*)d_in[2];
    const float* bq = (const float*)d_in[3];
    const float* Wk = (const float*)d_in[4];
    const float* bk = (const float*)d_in[5];
    const float* Wv = (const float*)d_in[6];
    const float* bv = (const float*)d_in[7];
    float* out = (float*)d_out;

    char* ws = (char*)d_ws;
    u16*   qbuf   = (u16*)(ws);                           // 4 MB
    u16*   kbuf   = (u16*)(ws + (4u  << 20));             // 4 MB
    u16*   vbuf   = (u16*)(ws + (8u  << 20));             // 4 MB
    u16*   hb     = (u16*)(ws + (12u << 20));             // 4 MB
    u16*   wt     = (u16*)(ws + (16u << 20));             // 1.5 MB
    float* pbias  = (float*)(ws + (18u << 20));           // 6 KB
    float* colsum = (float*)(ws + (18u << 20) + 8192);    // 2 KB

    hipMemsetAsync(colsum, 0, 512 * sizeof(float), stream);
    k_prep<<<dim3(2816), dim3(256), 0, stream>>>((const float4*)h, hb,
            Wq, Wk, Wv, bq, bk, bv, wt, pbias);
    k_gemm<<<dim3(32, 12), dim3(256), 0, stream>>>(hb, wt, pbias, qbuf, kbuf, vbuf, colsum);
    k_attn<<<dim3(2048), dim3(256), 0, stream>>>((const float4*)A, qbuf, kbuf, vbuf, colsum, out);
}

// Round 7
// 158.624 us; speedup vs baseline: 1.2888x; 1.2465x over previous
//
#include <hip/hip_runtime.h>

typedef unsigned short u16;
typedef unsigned short u16x8 __attribute__((ext_vector_type(8)));
typedef __bf16 bf16x8 __attribute__((ext_vector_type(8)));
typedef float f32x4 __attribute__((ext_vector_type(4)));

#define NN 4096
#define KD 512
#define HD 512
#define CAP 96   // per-row edge cap; mean 41, sigma 6.4, max≈71 -> safe

__device__ __forceinline__ u16 f2bf(float f) {
    unsigned u = __builtin_bit_cast(unsigned, f);
    u += 0x7fffu + ((u >> 16) & 1u);
    return (u16)(u >> 16);
}
__device__ __forceinline__ float bf2f(u16 u) {
    return __builtin_bit_cast(float, ((unsigned)u) << 16);
}
__device__ __forceinline__ int permj(int j) { return ((j & 7) << 6) | (j >> 3); }

#define GLOAD16(gp, lp) \
    __builtin_amdgcn_global_load_lds((const __attribute__((address_space(1))) void*)(gp), \
                                     (__attribute__((address_space(3))) void*)(lp), 16, 0, 0)

// ---- fused prep: h->bf16 | W^T bf16 head-major + bias | colsum zero ----
__global__ __launch_bounds__(256) void k_prep(const float4* __restrict__ h4,
        u16* __restrict__ hb,
        const float* __restrict__ Wq, const float* __restrict__ Wk,
        const float* __restrict__ Wv, const float* __restrict__ bq,
        const float* __restrict__ bk, const float* __restrict__ bv,
        u16* __restrict__ wt, float* __restrict__ pbias, float* __restrict__ colsum)
{
    __shared__ float tile[32][33];
    const int tid = threadIdx.x;
    if (blockIdx.x >= 2816) {                      // colsum zero block
        colsum[tid] = 0.f;
        colsum[tid + 256] = 0.f;
        return;
    }
    if (blockIdx.x < 2048) {
        int i = blockIdx.x * 256 + tid;
        float4 f = h4[i];
        ((ushort4*)hb)[i] = make_ushort4(f2bf(f.x), f2bf(f.y), f2bf(f.z), f2bf(f.w));
        return;
    }
    const int b2 = blockIdx.x - 2048;              // 0..767
    const int jb = b2 & 15, kb = (b2 >> 4) & 15, z = b2 >> 8;
    const float* W = (z == 0) ? Wq : ((z == 1) ? Wk : Wv);
    const float scale = (z == 0) ? 0.125f : 1.0f;
    const int j0 = jb * 32, k0 = kb * 32;
    const int tx = tid & 31, ty = tid >> 5;
    #pragma unroll
    for (int r = 0; r < 32; r += 8)
        tile[ty + r][tx] = W[(size_t)(k0 + ty + r) * HD + j0 + tx];
    __syncthreads();
    #pragma unroll
    for (int r = 0; r < 32; r += 8) {
        int j = j0 + ty + r;
        wt[(size_t)(z * 512 + permj(j)) * KD + k0 + tx] = f2bf(scale * tile[tx][ty + r]);
    }
    if (kb == 0 && ty == 0) {
        int j = j0 + tx;
        float b = (z == 0) ? bq[j] * 0.125f : ((z == 1) ? bk[j] : bv[j]);
        pbias[z * 512 + permj(j)] = b;
    }
}

// ---- QKV GEMM (m97-style) with fused v-colsum; q output bf16 ----
__global__ __launch_bounds__(256) void k_gemm(const u16* __restrict__ hb,
        const u16* __restrict__ wt, const float* __restrict__ pbias,
        u16* __restrict__ qbuf, u16* __restrict__ kbuf, u16* __restrict__ vbuf,
        float* __restrict__ colsum)
{
    __shared__ u16 As[128 * 64];
    __shared__ u16 Bs[128 * 64];
    const int tid = threadIdx.x;
    const int w = tid >> 6, lane = tid & 63;
    const int wr = w >> 1, wc = w & 1;
    const int l16 = lane & 15, half = lane >> 4;
    const int row0 = blockIdx.x * 128, col0 = blockIdx.y * 128;
    const int la = lane & 7, lb = lane >> 3;
    const int swcol = ((la ^ lb) << 3);

    const u16* gA[4]; const u16* gB[4];
    u16* lA[4]; u16* lB[4];
    #pragma unroll
    for (int s = 0; s < 4; ++s) {
        int i = w * 4 + s;
        gA[s] = hb + (size_t)(row0 + 8 * i + lb) * KD + swcol;
        gB[s] = wt + (size_t)(col0 + 8 * i + lb) * KD + swcol;
        lA[s] = As + i * 512;
        lB[s] = Bs + i * 512;
    }

    f32x4 acc[4][4] = {};

    for (int kk = 0; kk < KD; kk += 64) {
        #pragma unroll
        for (int s = 0; s < 4; ++s) {
            GLOAD16(gA[s] + kk, lA[s]);
            GLOAD16(gB[s] + kk, lB[s]);
        }
        __syncthreads();
        #pragma unroll
        for (int kk2 = 0; kk2 < 2; ++kk2) {
            bf16x8 af[4], bf[4];
            #pragma unroll
            for (int mi = 0; mi < 4; ++mi) {
                int row = wr * 64 + mi * 16 + l16;
                int off = row * 128 + (((kk2 << 6) | (half << 4)) ^ ((l16 & 7) << 4));
                af[mi] = *(const bf16x8*)((const char*)As + off);
            }
            #pragma unroll
            for (int ni = 0; ni < 4; ++ni) {
                int row = wc * 64 + ni * 16 + l16;
                int off = row * 128 + (((kk2 << 6) | (half << 4)) ^ ((l16 & 7) << 4));
                bf[ni] = *(const bf16x8*)((const char*)Bs + off);
            }
            #pragma unroll
            for (int mi = 0; mi < 4; ++mi)
                #pragma unroll
                for (int ni = 0; ni < 4; ++ni)
                    acc[mi][ni] = __builtin_amdgcn_mfma_f32_16x16x32_bf16(
                        af[mi], bf[ni], acc[mi][ni], 0, 0, 0);
        }
        __syncthreads();
    }

    const int seg = blockIdx.y >> 2;   // 0=q 1=k 2=v
    #pragma unroll
    for (int ni = 0; ni < 4; ++ni) {
        int j = col0 + wc * 64 + ni * 16 + l16;
        float bj = pbias[j];
        float csum = 0.f;
        #pragma unroll
        for (int mi = 0; mi < 4; ++mi) {
            #pragma unroll
            for (int r = 0; r < 4; ++r) {
                int m = row0 + wr * 64 + mi * 16 + half * 4 + r;
                float val = acc[mi][ni][r] + bj;
                if (seg == 0)      qbuf[(size_t)m * 512 + j] = f2bf(val);
                else if (seg == 1) kbuf[(size_t)m * 512 + (j - 512)] = f2bf(val);
                else             { vbuf[(size_t)m * 512 + (j - 1024)] = f2bf(val); csum += val; }
            }
        }
        if (seg == 2) {
            csum += __shfl_xor(csum, 16);
            csum += __shfl_xor(csum, 32);
            if (lane < 16) atomicAdd(&colsum[j - 1024], csum);
        }
    }
}

// ---- fused sparse attention: 1 row/block, 4 waves, wave-per-edge stride 4 ----
// Per edge: 16B k-load, 3 shfl intra-head reduce, shfl softmax across heads
// (every lane ends with its own head's coefficient), 16B v-load, 8 FMA.
// Unrolled x2 -> 4 independent 16B loads in flight. No LDS in the edge loop.
__global__ __launch_bounds__(256) void k_attn(const float4* __restrict__ A4,
        const u16* __restrict__ qbuf, const u16* __restrict__ kbuf,
        const u16* __restrict__ vbuf, const float* __restrict__ colsum,
        float* __restrict__ out)
{
    const int tid = threadIdx.x, w = tid >> 6, lane = tid & 63;
    const int n = blockIdx.x;
    __shared__ u16   s_idx[CAP];
    __shared__ int   s_cnt;
    __shared__ float s_red[4][512];   // 8 KB

    if (tid == 0) s_cnt = 0;
    __syncthreads();

    // per-lane fixed q chunk (head-major), unpacked to f32 once
    float qf[8];
    {
        u16x8 qv = *(const u16x8*)(qbuf + (size_t)n * 512 + lane * 8);
        #pragma unroll
        for (int j = 0; j < 8; ++j) qf[j] = bf2f(qv[j]);
    }

    // A-scan: 1 row = 1024 float4, 4 per thread
    {
        const float4* arow = A4 + (size_t)n * 1024;
        #pragma unroll
        for (int ii = 0; ii < 4; ++ii) {
            int i = ii * 256 + tid;
            float4 a = arow[i];
            if (a.x != 0.f || a.y != 0.f || a.z != 0.f || a.w != 0.f) {
                int m0 = i * 4;
                if (a.x != 0.f) { int p = atomicAdd(&s_cnt, 1); if (p < CAP) s_idx[p] = (u16)m0; }
                if (a.y != 0.f) { int p = atomicAdd(&s_cnt, 1); if (p < CAP) s_idx[p] = (u16)(m0 + 1); }
                if (a.z != 0.f) { int p = atomicAdd(&s_cnt, 1); if (p < CAP) s_idx[p] = (u16)(m0 + 2); }
                if (a.w != 0.f) { int p = atomicAdd(&s_cnt, 1); if (p < CAP) s_idx[p] = (u16)(m0 + 3); }
            }
        }
    }
    __syncthreads();
    const int cnt = min(s_cnt, CAP);

    float acc8[8] = {0.f,0.f,0.f,0.f,0.f,0.f,0.f,0.f};
    int e = w;
    for (; e + 4 < cnt; e += 8) {
        const int m0 = s_idx[e], m1 = s_idx[e + 4];
        u16x8 k0 = *(const u16x8*)(kbuf + (size_t)m0 * 512 + lane * 8);
        u16x8 k1 = *(const u16x8*)(kbuf + (size_t)m1 * 512 + lane * 8);
        u16x8 v0 = *(const u16x8*)(vbuf + (size_t)m0 * 512 + lane * 8);
        u16x8 v1 = *(const u16x8*)(vbuf + (size_t)m1 * 512 + lane * 8);
        float s0 = 0.f, s1 = 0.f;
        #pragma unroll
        for (int j = 0; j < 8; ++j) { s0 += qf[j] * bf2f(k0[j]); s1 += qf[j] * bf2f(k1[j]); }
        s0 += __shfl_xor(s0, 1); s1 += __shfl_xor(s1, 1);
        s0 += __shfl_xor(s0, 2); s1 += __shfl_xor(s1, 2);
        s0 += __shfl_xor(s0, 4); s1 += __shfl_xor(s1, 4);
        float mx0 = fmaxf(s0, __shfl_xor(s0, 8));
        float mx1 = fmaxf(s1, __shfl_xor(s1, 8));
        mx0 = fmaxf(mx0, __shfl_xor(mx0, 16)); mx1 = fmaxf(mx1, __shfl_xor(mx1, 16));
        mx0 = fmaxf(mx0, __shfl_xor(mx0, 32)); mx1 = fmaxf(mx1, __shfl_xor(mx1, 32));
        float e0 = __expf(s0 - mx0), e1 = __expf(s1 - mx1);
        float Z0 = e0 + __shfl_xor(e0, 8), Z1 = e1 + __shfl_xor(e1, 8);
        Z0 += __shfl_xor(Z0, 16); Z1 += __shfl_xor(Z1, 16);
        Z0 += __shfl_xor(Z0, 32); Z1 += __shfl_xor(Z1, 32);
        const float c0 = e0 / Z0 - 0.125f, c1 = e1 / Z1 - 0.125f;
        #pragma unroll
        for (int j = 0; j < 8; ++j)
            acc8[j] += c0 * bf2f(v0[j]) + c1 * bf2f(v1[j]);
    }
    for (; e < cnt; e += 4) {
        const int m0 = s_idx[e];
        u16x8 k0 = *(const u16x8*)(kbuf + (size_t)m0 * 512 + lane * 8);
        u16x8 v0 = *(const u16x8*)(vbuf + (size_t)m0 * 512 + lane * 8);
        float s0 = 0.f;
        #pragma unroll
        for (int j = 0; j < 8; ++j) s0 += qf[j] * bf2f(k0[j]);
        s0 += __shfl_xor(s0, 1);
        s0 += __shfl_xor(s0, 2);
        s0 += __shfl_xor(s0, 4);
        float mx0 = fmaxf(s0, __shfl_xor(s0, 8));
        mx0 = fmaxf(mx0, __shfl_xor(mx0, 16));
        mx0 = fmaxf(mx0, __shfl_xor(mx0, 32));
        float e0 = __expf(s0 - mx0);
        float Z0 = e0 + __shfl_xor(e0, 8);
        Z0 += __shfl_xor(Z0, 16);
        Z0 += __shfl_xor(Z0, 32);
        const float c0 = e0 / Z0 - 0.125f;
        #pragma unroll
        for (int j = 0; j < 8; ++j) acc8[j] += c0 * bf2f(v0[j]);
    }

    *(f32x4*)&s_red[w][lane * 8]     = *(f32x4*)&acc8[0];
    *(f32x4*)&s_red[w][lane * 8 + 4] = *(f32x4*)&acc8[4];
    __syncthreads();

    // epilogue: 512 outputs, 2 per thread
    #pragma unroll
    for (int pp = 0; pp < 2; ++pp) {
        int i2 = pp * 256 + tid;
        int hh2 = i2 >> 6, d = i2 & 63;
        float val = s_red[0][i2] + s_red[1][i2] + s_red[2][i2] + s_red[3][i2]
                  + 0.125f * colsum[i2];
        out[(size_t)hh2 * (NN * 64) + (size_t)n * 64 + d] = val;
    }
}

extern "C" void kernel_launch(void* const* d_in, const int* in_sizes, int n_in,
                              void* d_out, int out_size, void* d_ws, size_t ws_size,
                              hipStream_t stream)
{
    const float* A  = (const float*)d_in[0];
    const float* h  = (const float*)d_in[1];
    const float* Wq = (const float*)d_in[2];
    const float* bq = (const float*)d_in[3];
    const float* Wk = (const float*)d_in[4];
    const float* bk = (const float*)d_in[5];
    const float* Wv = (const float*)d_in[6];
    const float* bv = (const float*)d_in[7];
    float* out = (float*)d_out;

    char* ws = (char*)d_ws;
    u16*   qbuf   = (u16*)(ws);                           // 4 MB
    u16*   kbuf   = (u16*)(ws + (4u  << 20));             // 4 MB
    u16*   vbuf   = (u16*)(ws + (8u  << 20));             // 4 MB
    u16*   hb     = (u16*)(ws + (12u << 20));             // 4 MB
    u16*   wt     = (u16*)(ws + (16u << 20));             // 1.5 MB
    float* pbias  = (float*)(ws + (18u << 20));           // 6 KB
    float* colsum = (float*)(ws + (18u << 20) + 8192);    // 2 KB

    k_prep<<<dim3(2817), dim3(256), 0, stream>>>((const float4*)h, hb,
            Wq, Wk, Wv, bq, bk, bv, wt, pbias, colsum);
    k_gemm<<<dim3(32, 12), dim3(256), 0, stream>>>(hb, wt, pbias, qbuf, kbuf, vbuf, colsum);
    k_attn<<<dim3(4096), dim3(256), 0, stream>>>((const float4*)A, qbuf, kbuf, vbuf, colsum, out);
}

// Round 8
// 157.839 us; speedup vs baseline: 1.2952x; 1.0050x over previous
//
#include <hip/hip_runtime.h>

typedef unsigned short u16;
typedef unsigned short u16x8 __attribute__((ext_vector_type(8)));
typedef __bf16 bf16x8 __attribute__((ext_vector_type(8)));
typedef float f32x4 __attribute__((ext_vector_type(4)));

#define NN 4096
#define KD 512
#define HD 512
#define CAP 96   // per-row edge cap; mean 41, sigma 6.4, max≈71 -> safe

__device__ __forceinline__ u16 f2bf(float f) {
    unsigned u = __builtin_bit_cast(unsigned, f);
    u += 0x7fffu + ((u >> 16) & 1u);
    return (u16)(u >> 16);
}
__device__ __forceinline__ float bf2f(u16 u) {
    return __builtin_bit_cast(float, ((unsigned)u) << 16);
}
__device__ __forceinline__ int permj(int j) { return ((j & 7) << 6) | (j >> 3); }

#define GLOAD16(gp, lp) \
    __builtin_amdgcn_global_load_lds((const __attribute__((address_space(1))) void*)(gp), \
                                     (__attribute__((address_space(3))) void*)(lp), 16, 0, 0)

// ---- fused prep: h->bf16 | W^T bf16 head-major + bias | colsum zero ----
__global__ __launch_bounds__(256) void k_prep(const float4* __restrict__ h4,
        u16* __restrict__ hb,
        const float* __restrict__ Wq, const float* __restrict__ Wk,
        const float* __restrict__ Wv, const float* __restrict__ bq,
        const float* __restrict__ bk, const float* __restrict__ bv,
        u16* __restrict__ wt, float* __restrict__ pbias, float* __restrict__ colsum)
{
    __shared__ float tile[32][33];
    const int tid = threadIdx.x;
    if (blockIdx.x >= 2816) {                      // colsum zero block
        colsum[tid] = 0.f;
        colsum[tid + 256] = 0.f;
        return;
    }
    if (blockIdx.x < 2048) {
        int i = blockIdx.x * 256 + tid;
        float4 f = h4[i];
        ((ushort4*)hb)[i] = make_ushort4(f2bf(f.x), f2bf(f.y), f2bf(f.z), f2bf(f.w));
        return;
    }
    const int b2 = blockIdx.x - 2048;              // 0..767
    const int jb = b2 & 15, kb = (b2 >> 4) & 15, z = b2 >> 8;
    const float* W = (z == 0) ? Wq : ((z == 1) ? Wk : Wv);
    const float scale = (z == 0) ? 0.125f : 1.0f;
    const int j0 = jb * 32, k0 = kb * 32;
    const int tx = tid & 31, ty = tid >> 5;
    #pragma unroll
    for (int r = 0; r < 32; r += 8)
        tile[ty + r][tx] = W[(size_t)(k0 + ty + r) * HD + j0 + tx];
    __syncthreads();
    #pragma unroll
    for (int r = 0; r < 32; r += 8) {
        int j = j0 + ty + r;
        wt[(size_t)(z * 512 + permj(j)) * KD + k0 + tx] = f2bf(scale * tile[tx][ty + r]);
    }
    if (kb == 0 && ty == 0) {
        int j = j0 + tx;
        float b = (z == 0) ? bq[j] * 0.125f : ((z == 1) ? bk[j] : bv[j]);
        pbias[z * 512 + permj(j)] = b;
    }
}

// ---- QKV GEMM: BM=64, BN=128, BK=64 -> grid (64,12)=768 blocks, 3/CU ----
__global__ __launch_bounds__(256) void k_gemm(const u16* __restrict__ hb,
        const u16* __restrict__ wt, const float* __restrict__ pbias,
        u16* __restrict__ qbuf, u16* __restrict__ kbuf, u16* __restrict__ vbuf,
        float* __restrict__ colsum)
{
    __shared__ u16 As[64 * 64];    // 8 KB
    __shared__ u16 Bs[128 * 64];   // 16 KB
    const int tid = threadIdx.x;
    const int w = tid >> 6, lane = tid & 63;
    const int wr = w >> 1, wc = w & 1;         // wr: 32-row half, wc: 64-col half
    const int l16 = lane & 15, half = lane >> 4;
    const int row0 = blockIdx.x * 64, col0 = blockIdx.y * 128;
    const int la = lane & 7, lb = lane >> 3;
    const int swcol = ((la ^ lb) << 3);

    const u16* gA[2]; const u16* gB[4];
    u16* lA[2]; u16* lB[4];
    #pragma unroll
    for (int s = 0; s < 2; ++s) {
        int i = w * 2 + s;                      // 8 groups of 8 rows
        gA[s] = hb + (size_t)(row0 + 8 * i + lb) * KD + swcol;
        lA[s] = As + i * 512;
    }
    #pragma unroll
    for (int s = 0; s < 4; ++s) {
        int i = w * 4 + s;                      // 16 groups of 8 rows
        gB[s] = wt + (size_t)(col0 + 8 * i + lb) * KD + swcol;
        lB[s] = Bs + i * 512;
    }

    f32x4 acc[2][4] = {};

    for (int kk = 0; kk < KD; kk += 64) {
        #pragma unroll
        for (int s = 0; s < 2; ++s) GLOAD16(gA[s] + kk, lA[s]);
        #pragma unroll
        for (int s = 0; s < 4; ++s) GLOAD16(gB[s] + kk, lB[s]);
        __syncthreads();
        #pragma unroll
        for (int kk2 = 0; kk2 < 2; ++kk2) {
            bf16x8 af[2], bf[4];
            #pragma unroll
            for (int mi = 0; mi < 2; ++mi) {
                int row = wr * 32 + mi * 16 + l16;
                int off = row * 128 + (((kk2 << 6) | (half << 4)) ^ ((l16 & 7) << 4));
                af[mi] = *(const bf16x8*)((const char*)As + off);
            }
            #pragma unroll
            for (int ni = 0; ni < 4; ++ni) {
                int row = wc * 64 + ni * 16 + l16;
                int off = row * 128 + (((kk2 << 6) | (half << 4)) ^ ((l16 & 7) << 4));
                bf[ni] = *(const bf16x8*)((const char*)Bs + off);
            }
            #pragma unroll
            for (int mi = 0; mi < 2; ++mi)
                #pragma unroll
                for (int ni = 0; ni < 4; ++ni)
                    acc[mi][ni] = __builtin_amdgcn_mfma_f32_16x16x32_bf16(
                        af[mi], bf[ni], acc[mi][ni], 0, 0, 0);
        }
        __syncthreads();
    }

    const int seg = blockIdx.y >> 2;   // 0=q 1=k 2=v
    #pragma unroll
    for (int ni = 0; ni < 4; ++ni) {
        int j = col0 + wc * 64 + ni * 16 + l16;
        float bj = pbias[j];
        float csum = 0.f;
        #pragma unroll
        for (int mi = 0; mi < 2; ++mi) {
            #pragma unroll
            for (int r = 0; r < 4; ++r) {
                int m = row0 + wr * 32 + mi * 16 + half * 4 + r;
                float val = acc[mi][ni][r] + bj;
                if (seg == 0)      qbuf[(size_t)m * 512 + j] = f2bf(val);
                else if (seg == 1) kbuf[(size_t)m * 512 + (j - 512)] = f2bf(val);
                else             { vbuf[(size_t)m * 512 + (j - 1024)] = f2bf(val); csum += val; }
            }
        }
        if (seg == 2) {
            csum += __shfl_xor(csum, 16);
            csum += __shfl_xor(csum, 32);
            if (lane < 16) atomicAdd(&colsum[j - 1024], csum);
        }
    }
}

// ---- fused sparse attention: 1 row/block, 4 waves, wave-per-edge stride 4 ----
// x4 unroll -> 8 independent 16B gathers in flight per wave.
__global__ __launch_bounds__(256) void k_attn(const float4* __restrict__ A4,
        const u16* __restrict__ qbuf, const u16* __restrict__ kbuf,
        const u16* __restrict__ vbuf, const float* __restrict__ colsum,
        float* __restrict__ out)
{
    const int tid = threadIdx.x, w = tid >> 6, lane = tid & 63;
    const int n = blockIdx.x;
    __shared__ u16   s_idx[CAP];
    __shared__ int   s_cnt;
    __shared__ float s_red[4][512];   // 8 KB

    if (tid == 0) s_cnt = 0;
    __syncthreads();

    float qf[8];
    {
        u16x8 qv = *(const u16x8*)(qbuf + (size_t)n * 512 + lane * 8);
        #pragma unroll
        for (int j = 0; j < 8; ++j) qf[j] = bf2f(qv[j]);
    }

    // A-scan: 1 row = 1024 float4, 4 per thread
    {
        const float4* arow = A4 + (size_t)n * 1024;
        #pragma unroll
        for (int ii = 0; ii < 4; ++ii) {
            int i = ii * 256 + tid;
            float4 a = arow[i];
            if (a.x != 0.f || a.y != 0.f || a.z != 0.f || a.w != 0.f) {
                int m0 = i * 4;
                if (a.x != 0.f) { int p = atomicAdd(&s_cnt, 1); if (p < CAP) s_idx[p] = (u16)m0; }
                if (a.y != 0.f) { int p = atomicAdd(&s_cnt, 1); if (p < CAP) s_idx[p] = (u16)(m0 + 1); }
                if (a.z != 0.f) { int p = atomicAdd(&s_cnt, 1); if (p < CAP) s_idx[p] = (u16)(m0 + 2); }
                if (a.w != 0.f) { int p = atomicAdd(&s_cnt, 1); if (p < CAP) s_idx[p] = (u16)(m0 + 3); }
            }
        }
    }
    __syncthreads();
    const int cnt = min(s_cnt, CAP);
    const size_t loff = (size_t)(lane * 8);

    float acc8[8] = {0.f,0.f,0.f,0.f,0.f,0.f,0.f,0.f};
    int e = w;
    while (e + 12 < cnt) {
        const int m0 = s_idx[e], m1 = s_idx[e + 4], m2 = s_idx[e + 8], m3 = s_idx[e + 12];
        u16x8 k0 = *(const u16x8*)(kbuf + (size_t)m0 * 512 + loff);
        u16x8 k1 = *(const u16x8*)(kbuf + (size_t)m1 * 512 + loff);
        u16x8 k2 = *(const u16x8*)(kbuf + (size_t)m2 * 512 + loff);
        u16x8 k3 = *(const u16x8*)(kbuf + (size_t)m3 * 512 + loff);
        u16x8 v0 = *(const u16x8*)(vbuf + (size_t)m0 * 512 + loff);
        u16x8 v1 = *(const u16x8*)(vbuf + (size_t)m1 * 512 + loff);
        u16x8 v2 = *(const u16x8*)(vbuf + (size_t)m2 * 512 + loff);
        u16x8 v3 = *(const u16x8*)(vbuf + (size_t)m3 * 512 + loff);
        float s0 = 0.f, s1 = 0.f, s2 = 0.f, s3 = 0.f;
        #pragma unroll
        for (int j = 0; j < 8; ++j) {
            s0 += qf[j] * bf2f(k0[j]); s1 += qf[j] * bf2f(k1[j]);
            s2 += qf[j] * bf2f(k2[j]); s3 += qf[j] * bf2f(k3[j]);
        }
        s0 += __shfl_xor(s0, 1); s1 += __shfl_xor(s1, 1); s2 += __shfl_xor(s2, 1); s3 += __shfl_xor(s3, 1);
        s0 += __shfl_xor(s0, 2); s1 += __shfl_xor(s1, 2); s2 += __shfl_xor(s2, 2); s3 += __shfl_xor(s3, 2);
        s0 += __shfl_xor(s0, 4); s1 += __shfl_xor(s1, 4); s2 += __shfl_xor(s2, 4); s3 += __shfl_xor(s3, 4);
        float mx0 = fmaxf(s0, __shfl_xor(s0, 8)),  mx1 = fmaxf(s1, __shfl_xor(s1, 8));
        float mx2 = fmaxf(s2, __shfl_xor(s2, 8)),  mx3 = fmaxf(s3, __shfl_xor(s3, 8));
        mx0 = fmaxf(mx0, __shfl_xor(mx0, 16)); mx1 = fmaxf(mx1, __shfl_xor(mx1, 16));
        mx2 = fmaxf(mx2, __shfl_xor(mx2, 16)); mx3 = fmaxf(mx3, __shfl_xor(mx3, 16));
        mx0 = fmaxf(mx0, __shfl_xor(mx0, 32)); mx1 = fmaxf(mx1, __shfl_xor(mx1, 32));
        mx2 = fmaxf(mx2, __shfl_xor(mx2, 32)); mx3 = fmaxf(mx3, __shfl_xor(mx3, 32));
        float e0 = __expf(s0 - mx0), e1 = __expf(s1 - mx1);
        float e2 = __expf(s2 - mx2), e3 = __expf(s3 - mx3);
        float Z0 = e0 + __shfl_xor(e0, 8), Z1 = e1 + __shfl_xor(e1, 8);
        float Z2 = e2 + __shfl_xor(e2, 8), Z3 = e3 + __shfl_xor(e3, 8);
        Z0 += __shfl_xor(Z0, 16); Z1 += __shfl_xor(Z1, 16); Z2 += __shfl_xor(Z2, 16); Z3 += __shfl_xor(Z3, 16);
        Z0 += __shfl_xor(Z0, 32); Z1 += __shfl_xor(Z1, 32); Z2 += __shfl_xor(Z2, 32); Z3 += __shfl_xor(Z3, 32);
        const float c0 = e0 * __builtin_amdgcn_rcpf(Z0) - 0.125f;
        const float c1 = e1 * __builtin_amdgcn_rcpf(Z1) - 0.125f;
        const float c2 = e2 * __builtin_amdgcn_rcpf(Z2) - 0.125f;
        const float c3 = e3 * __builtin_amdgcn_rcpf(Z3) - 0.125f;
        #pragma unroll
        for (int j = 0; j < 8; ++j)
            acc8[j] += c0 * bf2f(v0[j]) + c1 * bf2f(v1[j])
                     + c2 * bf2f(v2[j]) + c3 * bf2f(v3[j]);
        e += 16;
    }
    while (e + 4 < cnt) {
        const int m0 = s_idx[e], m1 = s_idx[e + 4];
        u16x8 k0 = *(const u16x8*)(kbuf + (size_t)m0 * 512 + loff);
        u16x8 k1 = *(const u16x8*)(kbuf + (size_t)m1 * 512 + loff);
        u16x8 v0 = *(const u16x8*)(vbuf + (size_t)m0 * 512 + loff);
        u16x8 v1 = *(const u16x8*)(vbuf + (size_t)m1 * 512 + loff);
        float s0 = 0.f, s1 = 0.f;
        #pragma unroll
        for (int j = 0; j < 8; ++j) { s0 += qf[j] * bf2f(k0[j]); s1 += qf[j] * bf2f(k1[j]); }
        s0 += __shfl_xor(s0, 1); s1 += __shfl_xor(s1, 1);
        s0 += __shfl_xor(s0, 2); s1 += __shfl_xor(s1, 2);
        s0 += __shfl_xor(s0, 4); s1 += __shfl_xor(s1, 4);
        float mx0 = fmaxf(s0, __shfl_xor(s0, 8)), mx1 = fmaxf(s1, __shfl_xor(s1, 8));
        mx0 = fmaxf(mx0, __shfl_xor(mx0, 16)); mx1 = fmaxf(mx1, __shfl_xor(mx1, 16));
        mx0 = fmaxf(mx0, __shfl_xor(mx0, 32)); mx1 = fmaxf(mx1, __shfl_xor(mx1, 32));
        float e0 = __expf(s0 - mx0), e1 = __expf(s1 - mx1);
        float Z0 = e0 + __shfl_xor(e0, 8), Z1 = e1 + __shfl_xor(e1, 8);
        Z0 += __shfl_xor(Z0, 16); Z1 += __shfl_xor(Z1, 16);
        Z0 += __shfl_xor(Z0, 32); Z1 += __shfl_xor(Z1, 32);
        const float c0 = e0 * __builtin_amdgcn_rcpf(Z0) - 0.125f;
        const float c1 = e1 * __builtin_amdgcn_rcpf(Z1) - 0.125f;
        #pragma unroll
        for (int j = 0; j < 8; ++j)
            acc8[j] += c0 * bf2f(v0[j]) + c1 * bf2f(v1[j]);
        e += 8;
    }
    for (; e < cnt; e += 4) {
        const int m0 = s_idx[e];
        u16x8 k0 = *(const u16x8*)(kbuf + (size_t)m0 * 512 + loff);
        u16x8 v0 = *(const u16x8*)(vbuf + (size_t)m0 * 512 + loff);
        float s0 = 0.f;
        #pragma unroll
        for (int j = 0; j < 8; ++j) s0 += qf[j] * bf2f(k0[j]);
        s0 += __shfl_xor(s0, 1);
        s0 += __shfl_xor(s0, 2);
        s0 += __shfl_xor(s0, 4);
        float mx0 = fmaxf(s0, __shfl_xor(s0, 8));
        mx0 = fmaxf(mx0, __shfl_xor(mx0, 16));
        mx0 = fmaxf(mx0, __shfl_xor(mx0, 32));
        float e0 = __expf(s0 - mx0);
        float Z0 = e0 + __shfl_xor(e0, 8);
        Z0 += __shfl_xor(Z0, 16);
        Z0 += __shfl_xor(Z0, 32);
        const float c0 = e0 * __builtin_amdgcn_rcpf(Z0) - 0.125f;
        #pragma unroll
        for (int j = 0; j < 8; ++j) acc8[j] += c0 * bf2f(v0[j]);
    }

    *(f32x4*)&s_red[w][lane * 8]     = *(f32x4*)&acc8[0];
    *(f32x4*)&s_red[w][lane * 8 + 4] = *(f32x4*)&acc8[4];
    __syncthreads();

    #pragma unroll
    for (int pp = 0; pp < 2; ++pp) {
        int i2 = pp * 256 + tid;
        int hh2 = i2 >> 6, d = i2 & 63;
        float val = s_red[0][i2] + s_red[1][i2] + s_red[2][i2] + s_red[3][i2]
                  + 0.125f * colsum[i2];
        out[(size_t)hh2 * (NN * 64) + (size_t)n * 64 + d] = val;
    }
}

extern "C" void kernel_launch(void* const* d_in, const int* in_sizes, int n_in,
                              void* d_out, int out_size, void* d_ws, size_t ws_size,
                              hipStream_t stream)
{
    const float* A  = (const float*)d_in[0];
    const float* h  = (const float*)d_in[1];
    const float* Wq = (const float*)d_in[2];
    const float* bq = (const float*)d_in[3];
    const float* Wk = (const float*)d_in[4];
    const float* bk = (const float*)d_in[5];
    const float* Wv = (const float*)d_in[6];
    const float* bv = (const float*)d_in[7];
    float* out = (float*)d_out;

    char* ws = (char*)d_ws;
    u16*   qbuf   = (u16*)(ws);                           // 4 MB
    u16*   kbuf   = (u16*)(ws + (4u  << 20));             // 4 MB
    u16*   vbuf   = (u16*)(ws + (8u  << 20));             // 4 MB
    u16*   hb     = (u16*)(ws + (12u << 20));             // 4 MB
    u16*   wt     = (u16*)(ws + (16u << 20));             // 1.5 MB
    float* pbias  = (float*)(ws + (18u << 20));           // 6 KB
    float* colsum = (float*)(ws + (18u << 20) + 8192);    // 2 KB

    k_prep<<<dim3(2817), dim3(256), 0, stream>>>((const float4*)h, hb,
            Wq, Wk, Wv, bq, bk, bv, wt, pbias, colsum);
    k_gemm<<<dim3(64, 12), dim3(256), 0, stream>>>(hb, wt, pbias, qbuf, kbuf, vbuf, colsum);
    k_attn<<<dim3(4096), dim3(256), 0, stream>>>((const float4*)A, qbuf, kbuf, vbuf, colsum, out);
}